// Round 1
// baseline (2500.316 us; speedup 1.0000x reference)
//
#include <hip/hip_runtime.h>
#include <hip/hip_bf16.h>
#include <cstdint>
#include <cstddef>

#define LSEQ  64
#define BATCH 2048
#define HID   1024
#define NGATE 4096
#define VOC   256
#define EMBD  50

using bf16 = __hip_bfloat16;
typedef __attribute__((ext_vector_type(8))) __bf16 bf16x8;
typedef __attribute__((ext_vector_type(4))) float  f32x4;

__device__ __forceinline__ void gload_lds16(const void* g, void* l) {
  __builtin_amdgcn_global_load_lds(
      (const __attribute__((address_space(1))) unsigned int*)g,
      (__attribute__((address_space(3))) unsigned int*)l, 16, 0, 0);
}

__device__ __forceinline__ float sigf(float x) {
  x = fminf(fmaxf(x, -30.f), 30.f);
  return 1.f / (1.f + __expf(-x));
}
__device__ __forceinline__ float tanh_f(float x) {
  x = fminf(fmaxf(x, -15.f), 15.f);
  float e = __expf(2.f * x);
  return (e - 1.f) / (e + 1.f);
}

// ---------------- setup kernels (run every call; deterministic) ----------------

// Reorder W_hh rows so that within each 128-col N-tile the 4 gates of the same
// hidden unit sit in the 4 separate 16-col MFMA fragments of one wave:
// n' = T*128 + wc*64 + g*16 + hl  ->  orig row = g*1024 + T*32 + wc*16 + hl
__global__ void k_prep_whh(const float* __restrict__ W, bf16* __restrict__ Wr) {
  size_t i = (size_t)blockIdx.x * 256 + threadIdx.x;   // 4096*1024 total
  int k  = (int)(i & 1023);
  int np = (int)(i >> 10);
  int T = np >> 7, w = np & 127;
  int wc = w >> 6, g = (w >> 4) & 3, hl = w & 15;
  int grow = g * HID + T * 32 + wc * 16 + hl;
  Wr[i] = __float2bfloat16(W[(size_t)grow * HID + k]);
}

// embW[v][n'] = sum_e emb[v][e]*W_ih[row(n')][e] + b_ih[row] + b_hh[row], fp32
__global__ void k_prep_embw(const float* __restrict__ emb, const float* __restrict__ W_ih,
                            const float* __restrict__ b_ih, const float* __restrict__ b_hh,
                            float* __restrict__ embW) {
  size_t i = (size_t)blockIdx.x * 256 + threadIdx.x;   // 256*4096 total
  int np = (int)(i & 4095);
  int v  = (int)(i >> 12);
  int T = np >> 7, w = np & 127;
  int wc = w >> 6, g = (w >> 4) & 3, hl = w & 15;
  int grow = g * HID + T * 32 + wc * 16 + hl;
  float s = b_ih[grow] + b_hh[grow];
  #pragma unroll 10
  for (int e = 0; e < EMBD; ++e)
    s += emb[(size_t)v * EMBD + e] * W_ih[(size_t)grow * EMBD + e];
  embW[i] = s;
}

__global__ void k_prep_wp(const float* __restrict__ Wp_f, bf16* __restrict__ Wp) {
  size_t i = (size_t)blockIdx.x * 256 + threadIdx.x;   // 256*1024 total
  Wp[i] = __float2bfloat16(Wp_f[i]);
}

__global__ void k_init_state(const float* __restrict__ h0, const float* __restrict__ c0,
                             bf16* __restrict__ h, float* __restrict__ c) {
  size_t i = (size_t)blockIdx.x * 256 + threadIdx.x;   // 2048*1024 total
  h[i] = __float2bfloat16(h0[i]);
  c[i] = c0[i];
}

// ---------------- main step kernel ----------------
// mode 0: by<32 -> LSTM gates tile (128b x 32h, all 4 gates); by in [32,34) ->
//         projection of h_{t-1} -> scores[t-1] (skipped at t==0)
// mode 1: all blocks projection of h_in -> scores[63]
__global__ __launch_bounds__(256) void lstm_step_kernel(
    int t, int mode,
    const bf16* __restrict__ h_in, const float* __restrict__ c_in,
    bf16* __restrict__ h_out, float* __restrict__ c_out,
    const bf16* __restrict__ Wr, const bf16* __restrict__ Wp,
    const float* __restrict__ embW, const int* __restrict__ input,
    const float* __restrict__ b_proj, float* __restrict__ out)
{
  __shared__ __align__(16) bf16 lsA[128 * 32];
  __shared__ __align__(16) bf16 lsB[128 * 32];

  const int tid  = threadIdx.x;
  const int wave = tid >> 6, lane = tid & 63;
  const int wr = wave >> 1, wc = wave & 1;
  const int bx = blockIdx.x, by = blockIdx.y;

  const bool is_proj = (mode == 1) || (by >= 32);
  if (is_proj && mode == 0 && t == 0) return;
  const int nt = (mode == 1) ? by : (by - 32);

  const int bm0 = bx * 128;
  const bf16* Bsrc = is_proj ? (Wp + (size_t)nt * 128 * HID)
                             : (Wr + (size_t)by * 128 * HID);
  const bf16* Asrc = h_in + (size_t)bm0 * HID;

  // staging geometry: per round, 256 threads x 16B = 64 rows of 64B
  const int srow  = wave * 16 + (lane >> 2);  // + r*64
  const int skofs = (lane & 3) * 8;           // bf16 elems

  f32x4 acc[4][4] = {};

  for (int kt = 0; kt < 32; ++kt) {
    const int k0 = kt * 32;
    #pragma unroll
    for (int r = 0; r < 2; ++r) {
      const int row = r * 64 + srow;
      gload_lds16(Asrc + (size_t)row * HID + k0 + skofs, lsA + r * 2048 + wave * 512);
      gload_lds16(Bsrc + (size_t)row * HID + k0 + skofs, lsB + r * 2048 + wave * 512);
    }
    __syncthreads();
    bf16x8 aF[4], bF[4];
    #pragma unroll
    for (int m = 0; m < 4; ++m)
      aF[m] = *reinterpret_cast<const bf16x8*>(lsA + (wr * 64 + m * 16 + (lane & 15)) * 32 + (lane >> 4) * 8);
    #pragma unroll
    for (int n = 0; n < 4; ++n)
      bF[n] = *reinterpret_cast<const bf16x8*>(lsB + (wc * 64 + n * 16 + (lane & 15)) * 32 + (lane >> 4) * 8);
    #pragma unroll
    for (int m = 0; m < 4; ++m)
      #pragma unroll
      for (int n = 0; n < 4; ++n)
        acc[m][n] = __builtin_amdgcn_mfma_f32_16x16x32_bf16(aF[m], bF[n], acc[m][n], 0, 0, 0);
    __syncthreads();
  }

  const int hl   = lane & 15;
  const int qrow = (lane >> 4) * 4;

  if (!is_proj) {
    const int h_idx = by * 32 + wc * 16 + hl;
    const float* ewc = embW + (size_t)(by * 128 + wc * 64);
    #pragma unroll
    for (int m = 0; m < 4; ++m) {
      #pragma unroll
      for (int r = 0; r < 4; ++r) {
        const int b = bm0 + wr * 64 + m * 16 + qrow + r;
        const int idx = input[t * BATCH + b];
        const float* ew = ewc + (size_t)idx * NGATE;
        float iv = acc[m][0][r] + ew[hl];
        float fv = acc[m][1][r] + ew[16 + hl];
        float gv = acc[m][2][r] + ew[32 + hl];
        float ov = acc[m][3][r] + ew[48 + hl];
        const size_t off = (size_t)b * HID + h_idx;
        float cn = sigf(fv) * c_in[off] + sigf(iv) * tanh_f(gv);
        float hn = sigf(ov) * tanh_f(cn);
        h_out[off] = __float2bfloat16(hn);
        c_out[off] = cn;
        if (t == LSEQ - 1) {
          out[(size_t)LSEQ * BATCH * VOC + off] = hn;                          // hT
          out[(size_t)LSEQ * BATCH * VOC + (size_t)BATCH * HID + off] = cn;    // cT
        }
      }
    }
  } else {
    const int pt = (mode == 1) ? (LSEQ - 1) : (t - 1);
    float* os = out + (size_t)pt * BATCH * VOC;
    const int vbase = nt * 128 + wc * 64;
    #pragma unroll
    for (int m = 0; m < 4; ++m) {
      #pragma unroll
      for (int n = 0; n < 4; ++n) {
        const int v = vbase + n * 16 + hl;
        const float bp = b_proj[v];
        #pragma unroll
        for (int r = 0; r < 4; ++r) {
          const int b = bm0 + wr * 64 + m * 16 + qrow + r;
          os[(size_t)b * VOC + v] = acc[m][n][r] + bp;
        }
      }
    }
  }
}

// ---------------- host ----------------

extern "C" void kernel_launch(void* const* d_in, const int* in_sizes, int n_in,
                              void* d_out, int out_size, void* d_ws, size_t ws_size,
                              hipStream_t stream)
{
  (void)in_sizes; (void)n_in; (void)out_size; (void)ws_size;
  const int*   input  = (const int*)  d_in[0];
  const float* h0     = (const float*)d_in[1];
  const float* c0     = (const float*)d_in[2];
  const float* emb    = (const float*)d_in[3];
  const float* W_ih   = (const float*)d_in[4];
  const float* W_hh   = (const float*)d_in[5];
  const float* b_ih   = (const float*)d_in[6];
  const float* b_hh   = (const float*)d_in[7];
  const float* W_proj = (const float*)d_in[8];
  const float* b_proj = (const float*)d_in[9];
  float* out = (float*)d_out;

  char* ws = (char*)d_ws;
  bf16*  Wr   = (bf16*)(ws);               // 4096*1024*2 = 8,388,608
  bf16*  Wp   = (bf16*)(ws + 8388608);     //  256*1024*2 =   524,288
  float* embW = (float*)(ws + 8912896);    //  256*4096*4 = 4,194,304
  bf16*  hb0  = (bf16*)(ws + 13107200);    // 2048*1024*2 = 4,194,304
  bf16*  hb1  = (bf16*)(ws + 17301504);    // 2048*1024*2 = 4,194,304
  float* cb0  = (float*)(ws + 21495808);   // 2048*1024*4 = 8,388,608
  float* cb1  = (float*)(ws + 29884416);   // 2048*1024*4 = 8,388,608  (end ~36.5MB)

  k_prep_whh <<<16384, 256, 0, stream>>>(W_hh, Wr);
  k_prep_wp  <<<1024,  256, 0, stream>>>(W_proj, Wp);
  k_prep_embw<<<4096,  256, 0, stream>>>(emb, W_ih, b_ih, b_hh, embW);
  k_init_state<<<8192, 256, 0, stream>>>(h0, c0, hb0, cb0);

  bf16*  hbuf[2] = {hb0, hb1};
  float* cbuf[2] = {cb0, cb1};
  for (int t = 0; t < LSEQ; ++t) {
    lstm_step_kernel<<<dim3(16, 34), 256, 0, stream>>>(
        t, 0, hbuf[t & 1], cbuf[t & 1], hbuf[(t + 1) & 1], cbuf[(t + 1) & 1],
        Wr, Wp, embW, input, b_proj, out);
  }
  // scores[63] from h_63 (stored in hbuf[0])
  lstm_step_kernel<<<dim3(16, 2), 256, 0, stream>>>(
      63, 1, hbuf[0], cbuf[0], hbuf[1], cbuf[1],
      Wr, Wp, embW, input, b_proj, out);
}

// Round 2
// 2088.109 us; speedup vs baseline: 1.1974x; 1.1974x over previous
//
#include <hip/hip_runtime.h>
#include <hip/hip_bf16.h>
#include <cstdint>
#include <cstddef>

#define LSEQ  64
#define BATCH 2048
#define HID   1024
#define NGATE 4096
#define VOC   256
#define EMBD  50

using bf16 = __hip_bfloat16;
typedef __attribute__((ext_vector_type(8))) __bf16 bf16x8;
typedef __attribute__((ext_vector_type(4))) float  f32x4;

__device__ __forceinline__ void gload_lds16(const void* g, void* l) {
  __builtin_amdgcn_global_load_lds(
      (const __attribute__((address_space(1))) unsigned int*)g,
      (__attribute__((address_space(3))) unsigned int*)l, 16, 0, 0);
}

__device__ __forceinline__ float sigf(float x) {
  x = fminf(fmaxf(x, -30.f), 30.f);
  return 1.f / (1.f + __expf(-x));
}
__device__ __forceinline__ float tanh_f(float x) {
  x = fminf(fmaxf(x, -15.f), 15.f);
  float e = __expf(2.f * x);
  return (e - 1.f) / (e + 1.f);
}

// ---------------- setup kernels ----------------

// Reorder W_hh rows: n' = by*128 + wc*64 + g*16 + hl  ->  orig row g*1024 + by*32 + wc*16 + hl
__global__ void k_prep_whh(const float* __restrict__ W, bf16* __restrict__ Wr) {
  size_t i = (size_t)blockIdx.x * 256 + threadIdx.x;   // 4096*1024
  int k  = (int)(i & 1023);
  int np = (int)(i >> 10);
  int T = np >> 7, w = np & 127;
  int wc = w >> 6, g = (w >> 4) & 3, hl = w & 15;
  int grow = g * HID + T * 32 + wc * 16 + hl;
  Wr[i] = __float2bfloat16(W[(size_t)grow * HID + k]);
}

__global__ void k_prep_embw(const float* __restrict__ emb, const float* __restrict__ W_ih,
                            const float* __restrict__ b_ih, const float* __restrict__ b_hh,
                            float* __restrict__ embW) {
  size_t i = (size_t)blockIdx.x * 256 + threadIdx.x;   // 256*4096
  int np = (int)(i & 4095);
  int v  = (int)(i >> 12);
  int T = np >> 7, w = np & 127;
  int wc = w >> 6, g = (w >> 4) & 3, hl = w & 15;
  int grow = g * HID + T * 32 + wc * 16 + hl;
  float s = b_ih[grow] + b_hh[grow];
  #pragma unroll 10
  for (int e = 0; e < EMBD; ++e)
    s += emb[(size_t)v * EMBD + e] * W_ih[(size_t)grow * EMBD + e];
  embW[i] = s;
}

__global__ void k_prep_wp(const float* __restrict__ Wp_f, bf16* __restrict__ Wp) {
  size_t i = (size_t)blockIdx.x * 256 + threadIdx.x;   // 256*1024
  Wp[i] = __float2bfloat16(Wp_f[i]);
}

__global__ void k_init_state(const float* __restrict__ h0, const float* __restrict__ c0,
                             bf16* __restrict__ h, float* __restrict__ c) {
  size_t i = (size_t)blockIdx.x * 256 + threadIdx.x;   // 2048*1024
  h[i] = __float2bfloat16(h0[i]);
  c[i] = c0[i];
}

// ---------------- ring-4 counted-vmcnt GEMM kernel ----------------
// BM=256, BN=128, BK=32, 512 threads (8 waves as 4M x 2N), LDS ring of 4 K-tiles.
// MODE 0: gates step (A = h slot, B = Wr tile, LSTM-cell epilogue)
// MODE 1: projection  (A = stored h slots, B = Wp, scores epilogue)
template<int MODE>
__global__ __launch_bounds__(512) void g8(
    const bf16* __restrict__ Abase, const bf16* __restrict__ Bbase,
    const float* __restrict__ c_in, float* __restrict__ c_out,
    bf16* __restrict__ h_out,
    const float* __restrict__ embW, const int* __restrict__ input,
    const float* __restrict__ b_proj, float* __restrict__ out,
    int t, int kc, int nslots)
{
  __shared__ __align__(16) bf16 lsA[4 * 256 * 32];   // 64 KiB
  __shared__ __align__(16) bf16 lsB[4 * 128 * 32];   // 32 KiB

  const int tid  = threadIdx.x;
  const int wave = tid >> 6, lane = tid & 63;
  const int wr = wave >> 1, wc = wave & 1;
  const int bx = blockIdx.x, by = blockIdx.y;

  const bf16* Asrc;
  if constexpr (MODE == 0) {
    Asrc = Abase + (size_t)bx * 256 * HID;
  } else {
    int t_local = bx >> 3;
    int slot = (kc + 1 + t_local) % nslots;
    Asrc = Abase + ((size_t)slot * BATCH + (size_t)(bx & 7) * 256) * HID;
  }
  const bf16* Bsrc = Bbase + (size_t)by * 128 * HID;

  // ---- staging geometry (per thread): row = tid>>2 (unit0) / 128+ (unit1), granule tid&3
  // Source granule pre-permuted by the read-side XOR (rule 21: same involution both sides).
  const int srow = tid >> 2;                 // 0..127
  const int xg   = (tid >> 3) & 3;           // ((row>>1)&3), row-bit1..2 == tid-bit3..4
  const int colg = (((tid & 3) ^ xg) << 3);  // bf16 elems within 32-elem row chunk
  const bf16* pA0 = Asrc + (size_t)srow * HID + colg;
  const bf16* pA1 = Asrc + (size_t)(128 + srow) * HID + colg;
  const bf16* pB  = Bsrc + (size_t)srow * HID + colg;
  // wave-uniform LDS dst bases (elems); gload_lds writes lane*16B linearly
  bf16* dA0 = lsA + wave * 512;
  bf16* dA1 = lsA + 4096 + wave * 512;
  bf16* dB  = lsB + wave * 512;

  // ---- fragment read offsets (XOR-swizzled granule)
  const int hl = lane & 15;
  const int kk = (((lane >> 4) ^ ((lane >> 1) & 3)) << 3);  // swizzled granule * 8 elems
  int aofs[4], bofs[4];
  #pragma unroll
  for (int m = 0; m < 4; ++m) aofs[m] = (wr * 64 + m * 16 + hl) * 32 + kk;
  #pragma unroll
  for (int n = 0; n < 4; ++n) bofs[n] = (wc * 64 + n * 16 + hl) * 32 + kk;

  f32x4 acc[4][4] = {};

#define STAGE(SB_) do {                              \
    gload_lds16(pA0, dA0 + (SB_) * 8192); pA0 += 32; \
    gload_lds16(pA1, dA1 + (SB_) * 8192); pA1 += 32; \
    gload_lds16(pB,  dB  + (SB_) * 4096); pB  += 32; \
  } while (0)

#define TILE(S_, VM_, DOST_) do {                                        \
    asm volatile("s_waitcnt vmcnt(" #VM_ ")" ::: "memory");              \
    __builtin_amdgcn_s_barrier();                                        \
    __builtin_amdgcn_sched_barrier(0);                                   \
    const bf16* aB_ = lsA + (S_) * 8192;                                 \
    const bf16* bB_ = lsB + (S_) * 4096;                                 \
    bf16x8 aF[4], bF[4];                                                 \
    _Pragma("unroll")                                                    \
    for (int m = 0; m < 4; ++m) aF[m] = *(const bf16x8*)(aB_ + aofs[m]); \
    _Pragma("unroll")                                                    \
    for (int n = 0; n < 4; ++n) bF[n] = *(const bf16x8*)(bB_ + bofs[n]); \
    if (DOST_) STAGE(((S_) + 2) & 3);                                    \
    _Pragma("unroll")                                                    \
    for (int m = 0; m < 4; ++m)                                          \
      _Pragma("unroll")                                                  \
      for (int n = 0; n < 4; ++n)                                        \
        acc[m][n] = __builtin_amdgcn_mfma_f32_16x16x32_bf16(aF[m], bF[n], acc[m][n], 0, 0, 0); \
  } while (0)

  STAGE(0);   // k-tile 0
  STAGE(1);   // k-tile 1  (6 loads in flight)
  for (int kt = 0; kt < 28; kt += 4) {   // tiles 0..27, each stages tile+2
    TILE(0, 3, 1);
    TILE(1, 3, 1);
    TILE(2, 3, 1);
    TILE(3, 3, 1);
  }
  TILE(0, 3, 1);   // kt=28, stages 30
  TILE(1, 3, 1);   // kt=29, stages 31
  TILE(2, 3, 0);   // kt=30
  TILE(3, 0, 0);   // kt=31 (final drain)

#undef STAGE
#undef TILE

  const int qrow = (lane >> 4) * 4;

  if constexpr (MODE == 0) {
    const int h_idx = by * 32 + wc * 16 + hl;
    const float* ewc = embW + (size_t)(by * 128 + wc * 64);
    #pragma unroll
    for (int m = 0; m < 4; ++m) {
      const int b0 = bx * 256 + wr * 64 + m * 16 + qrow;
      const int4 iv = *(const int4*)(input + (size_t)t * BATCH + b0);
      #pragma unroll
      for (int r = 0; r < 4; ++r) {
        const int idx = (&iv.x)[r];
        const float* ew = ewc + (size_t)idx * NGATE;
        float ivv = acc[m][0][r] + ew[hl];
        float fv  = acc[m][1][r] + ew[16 + hl];
        float gv  = acc[m][2][r] + ew[32 + hl];
        float ov  = acc[m][3][r] + ew[48 + hl];
        const size_t off = (size_t)(b0 + r) * HID + h_idx;
        float cn = sigf(fv) * c_in[off] + sigf(ivv) * tanh_f(gv);
        float hn = sigf(ov) * tanh_f(cn);
        h_out[off] = __float2bfloat16(hn);
        c_out[off] = cn;
        if (t == LSEQ - 1) {
          out[(size_t)LSEQ * BATCH * VOC + off] = hn;                          // hT
          out[(size_t)LSEQ * BATCH * VOC + (size_t)BATCH * HID + off] = cn;    // cT
        }
      }
    }
  } else {
    const int t_glob = kc + (bx >> 3);
    float* os = out + (size_t)t_glob * BATCH * VOC;
    const int b0base = (bx & 7) * 256 + wr * 64;
    #pragma unroll
    for (int m = 0; m < 4; ++m) {
      #pragma unroll
      for (int n = 0; n < 4; ++n) {
        const int v = by * 128 + wc * 64 + n * 16 + hl;
        const float bp = b_proj[v];
        #pragma unroll
        for (int r = 0; r < 4; ++r)
          os[(size_t)(b0base + m * 16 + qrow + r) * VOC + v] = acc[m][n][r] + bp;
      }
    }
  }
}

// ---------------- host ----------------

extern "C" void kernel_launch(void* const* d_in, const int* in_sizes, int n_in,
                              void* d_out, int out_size, void* d_ws, size_t ws_size,
                              hipStream_t stream)
{
  (void)in_sizes; (void)n_in; (void)out_size;
  const int*   input  = (const int*)  d_in[0];
  const float* h0     = (const float*)d_in[1];
  const float* c0     = (const float*)d_in[2];
  const float* emb    = (const float*)d_in[3];
  const float* W_ih   = (const float*)d_in[4];
  const float* W_hh   = (const float*)d_in[5];
  const float* b_ih   = (const float*)d_in[6];
  const float* b_hh   = (const float*)d_in[7];
  const float* W_proj = (const float*)d_in[8];
  const float* b_proj = (const float*)d_in[9];
  float* out = (float*)d_out;

  char* ws = (char*)d_ws;
  bf16*  Wr   = (bf16*)(ws);               // 8,388,608 B
  bf16*  Wp   = (bf16*)(ws + 8388608);     //   524,288 B
  float* embW = (float*)(ws + 8912896);    // 4,194,304 B
  float* cb0  = (float*)(ws + 13107200);   // 8,388,608 B
  float* cb1  = (float*)(ws + 21495808);   // 8,388,608 B
  bf16*  hs   = (bf16*)(ws + 29884416);    // nslots * 4,194,304 B
  const size_t fixed = 29884416;
  const size_t slotB = (size_t)BATCH * HID * sizeof(bf16);   // 4,194,304

  // largest slot ring that fits: chunk = nslots-1 must divide 64
  int nslots = 2;
  const int cand[6] = {65, 17, 9, 5, 3, 2};
  for (int i = 0; i < 6; ++i)
    if (fixed + (size_t)cand[i] * slotB <= ws_size) { nslots = cand[i]; break; }
  const int chunk = nslots - 1;

  k_prep_whh <<<16384, 256, 0, stream>>>(W_hh, Wr);
  k_prep_wp  <<<1024,  256, 0, stream>>>(W_proj, Wp);
  k_prep_embw<<<4096,  256, 0, stream>>>(emb, W_ih, b_ih, b_hh, embW);
  k_init_state<<<8192, 256, 0, stream>>>(h0, c0, hs, cb0);   // h0 -> slot 0

  float* cbuf[2] = {cb0, cb1};
  for (int kc = 0; kc < LSEQ; kc += chunk) {
    for (int t = kc; t < kc + chunk; ++t) {
      const int si = t % nslots, so = (t + 1) % nslots;
      g8<0><<<dim3(8, 32), 512, 0, stream>>>(
          hs + (size_t)si * BATCH * HID, Wr,
          cbuf[t & 1], cbuf[(t + 1) & 1],
          hs + (size_t)so * BATCH * HID,
          embW, input, b_proj, out, t, 0, 0);
    }
    g8<1><<<dim3(8 * chunk, 2), 512, 0, stream>>>(
        hs, Wp, nullptr, nullptr, nullptr,
        nullptr, nullptr, b_proj, out, 0, kc, nslots);
  }
}

// Round 3
// 1888.059 us; speedup vs baseline: 1.3243x; 1.1060x over previous
//
#include <hip/hip_runtime.h>
#include <hip/hip_bf16.h>
#include <cstdint>
#include <cstddef>

#define LSEQ  64
#define BATCH 2048
#define HID   1024
#define NGATE 4096
#define VOC   256
#define EMBD  50

using bf16 = __hip_bfloat16;
typedef __attribute__((ext_vector_type(8))) __bf16 bf16x8;
typedef __attribute__((ext_vector_type(4))) float  f32x4;

__device__ __forceinline__ void gload_lds16(const void* g, void* l) {
  __builtin_amdgcn_global_load_lds(
      (const __attribute__((address_space(1))) unsigned int*)g,
      (__attribute__((address_space(3))) unsigned int*)l, 16, 0, 0);
}

__device__ __forceinline__ float sigf(float x) {
  x = fminf(fmaxf(x, -30.f), 30.f);
  return 1.f / (1.f + __expf(-x));
}
__device__ __forceinline__ float tanh_f(float x) {
  x = fminf(fmaxf(x, -15.f), 15.f);
  float e = __expf(2.f * x);
  return (e - 1.f) / (e + 1.f);
}

// ---------------- setup kernels ----------------

__global__ void k_prep_whh(const float* __restrict__ W, bf16* __restrict__ Wr) {
  size_t i = (size_t)blockIdx.x * 256 + threadIdx.x;   // 4096*1024
  int k  = (int)(i & 1023);
  int np = (int)(i >> 10);
  int T = np >> 7, w = np & 127;
  int wc = w >> 6, g = (w >> 4) & 3, hl = w & 15;
  int grow = g * HID + T * 32 + wc * 16 + hl;
  Wr[i] = __float2bfloat16(W[(size_t)grow * HID + k]);
}

__global__ void k_prep_embw(const float* __restrict__ emb, const float* __restrict__ W_ih,
                            const float* __restrict__ b_ih, const float* __restrict__ b_hh,
                            float* __restrict__ embW) {
  size_t i = (size_t)blockIdx.x * 256 + threadIdx.x;   // 256*4096
  int np = (int)(i & 4095);
  int v  = (int)(i >> 12);
  int T = np >> 7, w = np & 127;
  int wc = w >> 6, g = (w >> 4) & 3, hl = w & 15;
  int grow = g * HID + T * 32 + wc * 16 + hl;
  float s = b_ih[grow] + b_hh[grow];
  #pragma unroll 10
  for (int e = 0; e < EMBD; ++e)
    s += emb[(size_t)v * EMBD + e] * W_ih[(size_t)grow * EMBD + e];
  embW[i] = s;
}

__global__ void k_prep_wp(const float* __restrict__ Wp_f, bf16* __restrict__ Wp) {
  size_t i = (size_t)blockIdx.x * 256 + threadIdx.x;   // 256*1024
  Wp[i] = __float2bfloat16(Wp_f[i]);
}

__global__ void k_init_state(const float* __restrict__ h0, const float* __restrict__ c0,
                             bf16* __restrict__ h, float* __restrict__ c) {
  size_t i = (size_t)blockIdx.x * 256 + threadIdx.x;   // 2048*1024
  h[i] = __float2bfloat16(h0[i]);
  c[i] = c0[i];
}

// ---------------- phase-interleaved GEMM kernel ----------------
// BM=256, BN=128, BK=64, 512 threads (8 waves, 4M x 2N), LDS ring-3 of K-tiles.
// Per K-tile: entry {vmcnt(6); barrier}; 2 phases, each
// {8 ds_read; 3 gload_lds; barrier; lgkmcnt(0); sched_barrier; setprio(1); 16 MFMA; setprio(0)}.
template<int MODE>
__global__ __launch_bounds__(512) void g8(
    const bf16* __restrict__ Abase, const bf16* __restrict__ Bbase,
    const float* __restrict__ c_in, float* __restrict__ c_out,
    bf16* __restrict__ h_out,
    const float* __restrict__ embW, const int* __restrict__ input,
    const float* __restrict__ b_proj, float* __restrict__ out,
    int t, int kc, int nslots)
{
  __shared__ __align__(16) bf16 lsA[3 * 256 * 64];   // 96 KiB
  __shared__ __align__(16) bf16 lsB[3 * 128 * 64];   // 48 KiB

  const int tid  = threadIdx.x;
  const int wave = tid >> 6, lane = tid & 63;
  const int wr = wave >> 1, wc = wave & 1;
  const int hl = lane & 15, q = lane >> 4;

  int bx, by;
  if constexpr (MODE == 0) {
    // XCD-aware: by%8 == xcd -> each XCD re-reads only 4 Wr panels (1MB, L2-resident)
    int id = blockIdx.x, xcd = id & 7, idx = id >> 3;
    by = xcd + ((idx & 3) << 3);
    bx = idx >> 2;
  } else {
    bx = blockIdx.x; by = blockIdx.y;
  }

  const bf16* Asrc;
  if constexpr (MODE == 0) {
    Asrc = Abase + (size_t)bx * 256 * HID;
  } else {
    int t_local = bx >> 3;
    int slot = (kc + 1 + t_local) % nslots;
    Asrc = Abase + ((size_t)slot * BATCH + (size_t)(bx & 7) * 256) * HID;
  }
  const bf16* Bsrc = Bbase + (size_t)by * 128 * HID;

  // ---- staging source pointers: LDS granule (row,gl) holds global (row, gl^(row&7))
  const bf16 *pA0, *pA1, *pA2, *pA3, *pB0, *pB1;
  {
    int g0 = tid,      r0 = g0 >> 3, c0v = (g0 & 7) ^ (r0 & 7);
    int g1 = 512+tid,  r1 = g1 >> 3, c1v = (g1 & 7) ^ (r1 & 7);
    int g2 = 1024+tid, r2 = g2 >> 3, c2v = (g2 & 7) ^ (r2 & 7);
    int g3 = 1536+tid, r3 = g3 >> 3, c3v = (g3 & 7) ^ (r3 & 7);
    pA0 = Asrc + (size_t)r0 * HID + c0v * 8;
    pA1 = Asrc + (size_t)r1 * HID + c1v * 8;
    pA2 = Asrc + (size_t)r2 * HID + c2v * 8;
    pA3 = Asrc + (size_t)r3 * HID + c3v * 8;
    pB0 = Bsrc + (size_t)r0 * HID + c0v * 8;
    pB1 = Bsrc + (size_t)r1 * HID + c1v * 8;
  }
  bf16* dA = lsA + wave * 512;   // + S*16384 + j*4096 ; DMA adds lane*16B
  bf16* dB = lsB + wave * 512;   // + S*8192  + j*4096

  // ---- frag read offsets (row*64 + (g ^ (row&7))*8), g = ks*4 + q
  int aofs0[4], aofs1[4], bofs0[4], bofs1[4];
  #pragma unroll
  for (int m = 0; m < 4; ++m) {
    int row = wr * 64 + m * 16 + hl;
    aofs0[m] = row * 64 + ((q ^ (hl & 7)) * 8);
    aofs1[m] = row * 64 + (((4 + q) ^ (hl & 7)) * 8);
  }
  #pragma unroll
  for (int n = 0; n < 4; ++n) {
    int row = wc * 64 + n * 16 + hl;
    bofs0[n] = row * 64 + ((q ^ (hl & 7)) * 8);
    bofs1[n] = row * 64 + (((4 + q) ^ (hl & 7)) * 8);
  }

  f32x4 acc[4][4] = {};

#define STG_P0(S_) { gload_lds16(pA0, dA + (S_)*16384);         pA0 += 64;  \
                     gload_lds16(pA1, dA + (S_)*16384 + 4096);  pA1 += 64;  \
                     gload_lds16(pA2, dA + (S_)*16384 + 8192);  pA2 += 64; }
#define STG_P1(S_) { gload_lds16(pA3, dA + (S_)*16384 + 12288); pA3 += 64;  \
                     gload_lds16(pB0, dB + (S_)*8192);          pB0 += 64;  \
                     gload_lds16(pB1, dB + (S_)*8192 + 4096);   pB1 += 64; }

#define PHASE(Ab_, Bb_, AO_, BO_, STG_) {                                   \
    bf16x8 aF[4], bF[4];                                                    \
    _Pragma("unroll")                                                       \
    for (int m = 0; m < 4; ++m) aF[m] = *(const bf16x8*)((Ab_) + AO_[m]);   \
    _Pragma("unroll")                                                       \
    for (int n = 0; n < 4; ++n) bF[n] = *(const bf16x8*)((Bb_) + BO_[n]);   \
    STG_;                                                                   \
    __builtin_amdgcn_s_barrier();                                           \
    asm volatile("s_waitcnt lgkmcnt(0)" ::: "memory");                      \
    __builtin_amdgcn_sched_barrier(0);                                      \
    __builtin_amdgcn_s_setprio(1);                                          \
    _Pragma("unroll")                                                       \
    for (int m = 0; m < 4; ++m)                                             \
      _Pragma("unroll")                                                     \
      for (int n = 0; n < 4; ++n)                                           \
        acc[m][n] = __builtin_amdgcn_mfma_f32_16x16x32_bf16(aF[m], bF[n], acc[m][n], 0, 0, 0); \
    __builtin_amdgcn_s_setprio(0);                                          \
  }

  // prologue: stage K-tiles 0,1
  STG_P0(0); STG_P1(0);
  STG_P0(1); STG_P1(1);
  __builtin_amdgcn_sched_barrier(0);

  int cur = 0, st = 2;
  for (int T = 0; T < 15; ++T) {
    asm volatile("s_waitcnt vmcnt(6)" ::: "memory");
    __builtin_amdgcn_s_barrier();
    const bf16* Ab = lsA + cur * 16384;
    const bf16* Bb = lsB + cur * 8192;
    if (T < 14) {
      PHASE(Ab, Bb, aofs0, bofs0, STG_P0(st));
      PHASE(Ab, Bb, aofs1, bofs1, STG_P1(st));
    } else {
      PHASE(Ab, Bb, aofs0, bofs0, );
      PHASE(Ab, Bb, aofs1, bofs1, );
    }
    cur = (cur == 2) ? 0 : cur + 1;
    st  = (st  == 2) ? 0 : st  + 1;
  }
  asm volatile("s_waitcnt vmcnt(0)" ::: "memory");
  __builtin_amdgcn_s_barrier();
  {
    const bf16* Ab = lsA + cur * 16384;
    const bf16* Bb = lsB + cur * 8192;
    PHASE(Ab, Bb, aofs0, bofs0, );
    PHASE(Ab, Bb, aofs1, bofs1, );
  }
  __builtin_amdgcn_sched_barrier(0);

#undef STG_P0
#undef STG_P1
#undef PHASE

  const int qrow = q * 4;

  if constexpr (MODE == 0) {
    const int h_idx = by * 32 + wc * 16 + hl;
    const float* ewc = embW + (size_t)(by * 128 + wc * 64);
    #pragma unroll
    for (int m = 0; m < 4; ++m) {
      const int b0 = bx * 256 + wr * 64 + m * 16 + qrow;
      const int4 iv = *(const int4*)(input + (size_t)t * BATCH + b0);
      #pragma unroll
      for (int r = 0; r < 4; ++r) {
        const int idx = (&iv.x)[r];
        const float* ew = ewc + (size_t)idx * NGATE;
        float ivv = acc[m][0][r] + ew[hl];
        float fv  = acc[m][1][r] + ew[16 + hl];
        float gv  = acc[m][2][r] + ew[32 + hl];
        float ov  = acc[m][3][r] + ew[48 + hl];
        const size_t off = (size_t)(b0 + r) * HID + h_idx;
        float cn = sigf(fv) * c_in[off] + sigf(ivv) * tanh_f(gv);
        float hn = sigf(ov) * tanh_f(cn);
        h_out[off] = __float2bfloat16(hn);
        c_out[off] = cn;
        if (t == LSEQ - 1) {
          out[(size_t)LSEQ * BATCH * VOC + off] = hn;                          // hT
          out[(size_t)LSEQ * BATCH * VOC + (size_t)BATCH * HID + off] = cn;    // cT
        }
      }
    }
  } else {
    const int t_glob = kc + (bx >> 3);
    float* os = out + (size_t)t_glob * BATCH * VOC;
    const int b0base = (bx & 7) * 256 + wr * 64;
    #pragma unroll
    for (int m = 0; m < 4; ++m) {
      #pragma unroll
      for (int n = 0; n < 4; ++n) {
        const int v = by * 128 + wc * 64 + n * 16 + hl;
        const float bp = b_proj[v];
        #pragma unroll
        for (int r = 0; r < 4; ++r)
          os[(size_t)(b0base + m * 16 + qrow + r) * VOC + v] = acc[m][n][r] + bp;
      }
    }
  }
}

// ---------------- host ----------------

extern "C" void kernel_launch(void* const* d_in, const int* in_sizes, int n_in,
                              void* d_out, int out_size, void* d_ws, size_t ws_size,
                              hipStream_t stream)
{
  (void)in_sizes; (void)n_in; (void)out_size;
  const int*   input  = (const int*)  d_in[0];
  const float* h0     = (const float*)d_in[1];
  const float* c0     = (const float*)d_in[2];
  const float* emb    = (const float*)d_in[3];
  const float* W_ih   = (const float*)d_in[4];
  const float* W_hh   = (const float*)d_in[5];
  const float* b_ih   = (const float*)d_in[6];
  const float* b_hh   = (const float*)d_in[7];
  const float* W_proj = (const float*)d_in[8];
  const float* b_proj = (const float*)d_in[9];
  float* out = (float*)d_out;

  char* ws = (char*)d_ws;
  bf16*  Wr   = (bf16*)(ws);               // 8,388,608 B
  bf16*  Wp   = (bf16*)(ws + 8388608);     //   524,288 B
  float* embW = (float*)(ws + 8912896);    // 4,194,304 B
  float* cb0  = (float*)(ws + 13107200);   // 8,388,608 B
  float* cb1  = (float*)(ws + 21495808);   // 8,388,608 B
  bf16*  hs   = (bf16*)(ws + 29884416);    // nslots * 4,194,304 B
  const size_t fixed = 29884416;
  const size_t slotB = (size_t)BATCH * HID * sizeof(bf16);   // 4,194,304

  int nslots = 2;
  const int cand[6] = {65, 17, 9, 5, 3, 2};
  for (int i = 0; i < 6; ++i)
    if (fixed + (size_t)cand[i] * slotB <= ws_size) { nslots = cand[i]; break; }
  const int chunk = nslots - 1;

  k_prep_whh <<<16384, 256, 0, stream>>>(W_hh, Wr);
  k_prep_wp  <<<1024,  256, 0, stream>>>(W_proj, Wp);
  k_prep_embw<<<4096,  256, 0, stream>>>(emb, W_ih, b_ih, b_hh, embW);
  k_init_state<<<8192, 256, 0, stream>>>(h0, c0, hs, cb0);   // h0 -> slot 0

  float* cbuf[2] = {cb0, cb1};
  for (int kc = 0; kc < LSEQ; kc += chunk) {
    for (int t = kc; t < kc + chunk; ++t) {
      const int si = t % nslots, so = (t + 1) % nslots;
      g8<0><<<dim3(256), 512, 0, stream>>>(
          hs + (size_t)si * BATCH * HID, Wr,
          cbuf[t & 1], cbuf[(t + 1) & 1],
          hs + (size_t)so * BATCH * HID,
          embW, input, b_proj, out, t, 0, 0);
    }
    g8<1><<<dim3(8 * chunk, 2), 512, 0, stream>>>(
        hs, Wp, nullptr, nullptr, nullptr,
        nullptr, nullptr, b_proj, out, 0, kc, nslots);
  }
}